// Round 1
// baseline (1273.924 us; speedup 1.0000x reference)
//
#include <hip/hip_runtime.h>
#include <math.h>

#define N_NODES 100000
#define N_EDGES 1600000
#define HDIM    256
#define NGRAPH  64

// ---------------- utility ----------------
__global__ void k_zero_int(int* __restrict__ p, int n) {
    int i = blockIdx.x * blockDim.x + threadIdx.x;
    if (i < n) p[i] = 0;
}

// count in-degree (dst side)
__global__ void k_count(const int* __restrict__ ei, int* __restrict__ cnt) {
    int e = blockIdx.x * blockDim.x + threadIdx.x;
    if (e < N_EDGES) atomicAdd(&cnt[ei[N_EDGES + e]], 1);
}

// exclusive scan of cnt[N] -> rowptr[N+1], single block of 1024 threads
__global__ __launch_bounds__(1024) void k_scan(const int* __restrict__ cnt,
                                               int* __restrict__ rowptr) {
    __shared__ int lds[1024];
    int t = threadIdx.x;
    const int chunk = (N_NODES + 1023) / 1024;  // 98
    int i0 = t * chunk;
    int i1 = min(i0 + chunk, N_NODES);
    int s = 0;
    for (int i = i0; i < i1; ++i) s += cnt[i];
    lds[t] = s;
    __syncthreads();
    for (int off = 1; off < 1024; off <<= 1) {
        int v = (t >= off) ? lds[t - off] : 0;
        __syncthreads();
        lds[t] += v;
        __syncthreads();
    }
    int run = (t == 0) ? 0 : lds[t - 1];
    for (int i = i0; i < i1; ++i) { rowptr[i] = run; run += cnt[i]; }
    if (t == 1023) rowptr[N_NODES] = lds[1023];
}

// dinv = 1/sqrt(deg+1); xd = x*dinv; fill counter reset
__global__ void k_dinv(const int* __restrict__ cnt, const float* __restrict__ x,
                       float* __restrict__ dinv, float* __restrict__ xd,
                       int* __restrict__ fill) {
    int i = blockIdx.x * blockDim.x + threadIdx.x;
    if (i < N_NODES) {
        float d = (float)(cnt[i] + 1);
        float dv = 1.0f / sqrtf(d);
        dinv[i] = dv;
        xd[i] = x[i] * dv;
        fill[i] = 0;
    }
}

// CSR fill: col[pos] = src for each dst
__global__ void k_fill(const int* __restrict__ ei, const int* __restrict__ rowptr,
                       int* __restrict__ fill, int* __restrict__ colv) {
    int e = blockIdx.x * blockDim.x + threadIdx.x;
    if (e < N_EDGES) {
        int d = ei[N_EDGES + e];
        int pos = rowptr[d] + atomicAdd(&fill[d], 1);
        colv[pos] = ei[e];
    }
}

// layer-1 scalar aggregation: s[i] = dinv[i]*(xd[i] + sum_{src in N(i)} xd[src])
__global__ void k_s(const int* __restrict__ rowptr, const int* __restrict__ colv,
                    const float* __restrict__ xd, const float* __restrict__ dinv,
                    float* __restrict__ sv) {
    int i = blockIdx.x * blockDim.x + threadIdx.x;
    if (i >= N_NODES) return;
    float acc = xd[i];
    int s = rowptr[i], e = rowptr[i + 1];
    for (int k = s; k < e; ++k) acc += xd[colv[k]];
    sv[i] = dinv[i] * acc;
}

// h1[i][j] = relu(s[i]*W1[j] + b1[j]); one wave per node
__global__ __launch_bounds__(256) void k_h1(const float* __restrict__ sv,
                                            const float* __restrict__ W1,
                                            const float* __restrict__ b1,
                                            float* __restrict__ h) {
    int wid = threadIdx.x >> 6, lane = threadIdx.x & 63;
    int node = blockIdx.x * 4 + wid;
    if (node >= N_NODES) return;
    int c4 = lane * 4;
    float s = sv[node];
    float4 w = *(const float4*)&W1[c4];
    float4 b = *(const float4*)&b1[c4];
    float4 o;
    o.x = fmaxf(s * w.x + b.x, 0.f);
    o.y = fmaxf(s * w.y + b.y, 0.f);
    o.z = fmaxf(s * w.z + b.z, 0.f);
    o.w = fmaxf(s * w.w + b.w, 0.f);
    *(float4*)&h[(size_t)node * HDIM + c4] = o;
}

// ---------------- GEMM: C[r][c] = dinv[r] * sum_k A[r][k]*W[k][c] ----------------
#define BM 128
#define BN 64
#define BK 16

__global__ __launch_bounds__(256) void k_gemm_scale(const float* __restrict__ A,
                                                    const float* __restrict__ W,
                                                    const float* __restrict__ dinv,
                                                    float* __restrict__ C) {
    __shared__ __align__(16) float As[BK][BM + 4];  // LD=132: aligned f4, 2-way-max banks
    __shared__ __align__(16) float Bs[BK][BN];
    int tid = threadIdx.x;
    int row0 = blockIdx.x * BM;
    int col0 = blockIdx.y * BN;
    int ty = tid >> 4, tx = tid & 15;  // 16x16 threads; thread tile 8x4

    float acc[8][4];
#pragma unroll
    for (int i = 0; i < 8; ++i)
#pragma unroll
        for (int j = 0; j < 4; ++j) acc[i][j] = 0.f;

#pragma unroll 1
    for (int kt = 0; kt < HDIM / BK; ++kt) {
        // load A tile: 128x16 floats = 512 float4, 2 per thread
        float4 av[2];
        int rowA[2], kqA[2];
#pragma unroll
        for (int q = 0; q < 2; ++q) {
            int idx = tid * 2 + q;
            rowA[q] = idx >> 2;
            kqA[q] = idx & 3;
            int gr = row0 + rowA[q];
            if (gr < N_NODES)
                av[q] = *(const float4*)&A[(size_t)gr * HDIM + kt * BK + kqA[q] * 4];
            else
                av[q] = make_float4(0.f, 0.f, 0.f, 0.f);
        }
        // load B tile: 16x64 = 256 float4, 1 per thread
        int kb = tid >> 4, cq = tid & 15;
        float4 bv = *(const float4*)&W[(size_t)(kt * BK + kb) * HDIM + col0 + cq * 4];

        __syncthreads();
#pragma unroll
        for (int q = 0; q < 2; ++q) {
            As[kqA[q] * 4 + 0][rowA[q]] = av[q].x;
            As[kqA[q] * 4 + 1][rowA[q]] = av[q].y;
            As[kqA[q] * 4 + 2][rowA[q]] = av[q].z;
            As[kqA[q] * 4 + 3][rowA[q]] = av[q].w;
        }
        *(float4*)&Bs[kb][cq * 4] = bv;
        __syncthreads();

#pragma unroll
        for (int k = 0; k < BK; ++k) {
            float4 a0 = *(const float4*)&As[k][ty * 8];
            float4 a1 = *(const float4*)&As[k][ty * 8 + 4];
            float4 b0 = *(const float4*)&Bs[k][tx * 4];
            float a[8] = {a0.x, a0.y, a0.z, a0.w, a1.x, a1.y, a1.z, a1.w};
            float b[4] = {b0.x, b0.y, b0.z, b0.w};
#pragma unroll
            for (int i = 0; i < 8; ++i)
#pragma unroll
                for (int j = 0; j < 4; ++j) acc[i][j] = fmaf(a[i], b[j], acc[i][j]);
        }
    }

#pragma unroll
    for (int i = 0; i < 8; ++i) {
        int r = row0 + ty * 8 + i;
        if (r < N_NODES) {
            float dv = dinv[r];
            float4 o = make_float4(acc[i][0] * dv, acc[i][1] * dv, acc[i][2] * dv,
                                   acc[i][3] * dv);
            *(float4*)&C[(size_t)r * HDIM + col0 + tx * 4] = o;
        }
    }
}

// aggregation: h[i] = relu(dinv[i]*(g[i] + sum_src g[src]) + b); one wave per node
__global__ __launch_bounds__(256) void k_agg(const float* __restrict__ g,
                                             const int* __restrict__ rowptr,
                                             const int* __restrict__ colv,
                                             const float* __restrict__ dinv,
                                             const float* __restrict__ bias,
                                             float* __restrict__ hout) {
    int wid = threadIdx.x >> 6, lane = threadIdx.x & 63;
    int node = blockIdx.x * 4 + wid;
    if (node >= N_NODES) return;
    int c4 = lane * 4;
    float4 bv = *(const float4*)&bias[c4];
    float4 acc = *(const float4*)&g[(size_t)node * HDIM + c4];
    int s = rowptr[node], e = rowptr[node + 1];
    for (int i = s; i < e; ++i) {
        int src = colv[i];
        float4 v = *(const float4*)&g[(size_t)src * HDIM + c4];
        acc.x += v.x; acc.y += v.y; acc.z += v.z; acc.w += v.w;
    }
    float dv = dinv[node];
    float4 o;
    o.x = fmaxf(fmaf(acc.x, dv, bv.x), 0.f);
    o.y = fmaxf(fmaf(acc.y, dv, bv.y), 0.f);
    o.z = fmaxf(fmaf(acc.z, dv, bv.z), 0.f);
    o.w = fmaxf(fmaf(acc.w, dv, bv.w), 0.f);
    *(float4*)&hout[(size_t)node * HDIM + c4] = o;
}

// segment boundaries via binary search + zero pooled accumulator
__global__ __launch_bounds__(128) void k_bounds(const int* __restrict__ batch,
                                                int* __restrict__ startb,
                                                float* __restrict__ pooled) {
    int t = threadIdx.x;
    if (t <= NGRAPH) {
        int lo = 0, hi = N_NODES;
        while (lo < hi) {
            int mid = (lo + hi) >> 1;
            if (batch[mid] < t) lo = mid + 1; else hi = mid;
        }
        startb[t] = lo;
    }
    for (int i = t; i < NGRAPH * HDIM; i += 128) pooled[i] = 0.f;
}

// chunked mean-pool partial sums
__global__ __launch_bounds__(256) void k_pool(const float* __restrict__ h,
                                              const int* __restrict__ startb,
                                              float* __restrict__ pooled) {
    int b = blockIdx.x >> 3, c = blockIdx.x & 7;
    int s0 = startb[b], e0 = startb[b + 1];
    int len = e0 - s0;
    if (len <= 0) return;
    int per = (len + 7) >> 3;
    int is = s0 + c * per;
    int ie = min(is + per, e0);
    if (is >= ie) return;
    int j = threadIdx.x;
    float sum = 0.f;
    for (int n = is; n < ie; ++n) sum += h[(size_t)n * HDIM + j];
    atomicAdd(&pooled[b * HDIM + j], sum);
}

// feat[b][j] = pooled/cnt;  feat[b][256] = svm[b]
__global__ __launch_bounds__(256) void k_feat(const float* __restrict__ pooled,
                                              const int* __restrict__ startb,
                                              const float* __restrict__ svm,
                                              float* __restrict__ feat) {
    int b = blockIdx.x;
    int j = threadIdx.x;
    float cntb = (float)(startb[b + 1] - startb[b]);
    cntb = fmaxf(cntb, 1.0f);
    feat[b * 257 + j] = pooled[b * HDIM + j] / cntb;
    if (j == 0) feat[b * 257 + 256] = svm[b];
}

// final MLP: out = relu(feat@Wf1+bf1)@Wf2+bf2
__global__ __launch_bounds__(128) void k_mlp(const float* __restrict__ feat,
                                             const float* __restrict__ Wf1,
                                             const float* __restrict__ bf1,
                                             const float* __restrict__ Wf2,
                                             const float* __restrict__ bf2,
                                             float* __restrict__ out) {
    __shared__ float fl[257];
    __shared__ float hl[128];
    int b = blockIdx.x;
    int j = threadIdx.x;
    for (int k = j; k < 257; k += 128) fl[k] = feat[b * 257 + k];
    __syncthreads();
    float acc = bf1[j];
    for (int k = 0; k < 257; ++k) acc = fmaf(fl[k], Wf1[k * 128 + j], acc);
    hl[j] = fmaxf(acc, 0.f);
    __syncthreads();
    if (j < 6) {
        float o = bf2[j];
        for (int k = 0; k < 128; ++k) o = fmaf(hl[k], Wf2[k * 6 + j], o);
        out[b * 6 + j] = o;
    }
}

static inline size_t al256(size_t x) { return (x + 255) & ~(size_t)255; }

extern "C" void kernel_launch(void* const* d_in, const int* in_sizes, int n_in,
                              void* d_out, int out_size, void* d_ws, size_t ws_size,
                              hipStream_t stream) {
    const float* x    = (const float*)d_in[0];
    const int*   ei   = (const int*)d_in[1];   // [2][E]
    const int*   batch= (const int*)d_in[2];
    const float* svm  = (const float*)d_in[3];
    const float* W1   = (const float*)d_in[4];
    const float* b1   = (const float*)d_in[5];
    const float* W2   = (const float*)d_in[6];
    const float* b2   = (const float*)d_in[7];
    const float* W3   = (const float*)d_in[8];
    const float* b3   = (const float*)d_in[9];
    const float* Wf1  = (const float*)d_in[10];
    const float* bf1  = (const float*)d_in[11];
    const float* Wf2  = (const float*)d_in[12];
    const float* bf2  = (const float*)d_in[13];
    float* out = (float*)d_out;

    char* w = (char*)d_ws;
    int*   cnt    = (int*)w;    w += al256((size_t)N_NODES * 4);
    int*   rowptr = (int*)w;    w += al256((size_t)(N_NODES + 1) * 4);
    int*   fill   = (int*)w;    w += al256((size_t)N_NODES * 4);
    int*   colv   = (int*)w;    w += al256((size_t)N_EDGES * 4);
    float* dinv   = (float*)w;  w += al256((size_t)N_NODES * 4);
    float* xd     = (float*)w;  w += al256((size_t)N_NODES * 4);
    float* sv     = (float*)w;  w += al256((size_t)N_NODES * 4);
    int*   startb = (int*)w;    w += al256(65 * 4);
    float* pooled = (float*)w;  w += al256((size_t)NGRAPH * HDIM * 4);
    float* feat   = (float*)w;  w += al256((size_t)NGRAPH * 257 * 4);
    float* bigA   = (float*)w;  w += al256((size_t)N_NODES * HDIM * 4);
    float* bigB   = (float*)w;  w += al256((size_t)N_NODES * HDIM * 4);

    const int nblkN  = (N_NODES + 255) / 256;
    const int nblkE  = (N_EDGES + 255) / 256;
    const int nblkW  = (N_NODES + 3) / 4;  // one wave per node, 4 waves/block

    // CSR build
    k_zero_int<<<nblkN, 256, 0, stream>>>(cnt, N_NODES);
    k_count<<<nblkE, 256, 0, stream>>>(ei, cnt);
    k_scan<<<1, 1024, 0, stream>>>(cnt, rowptr);
    k_dinv<<<nblkN, 256, 0, stream>>>(cnt, x, dinv, xd, fill);
    k_fill<<<nblkE, 256, 0, stream>>>(ei, rowptr, fill, colv);

    // layer 1 (rank-1)
    k_s<<<nblkN, 256, 0, stream>>>(rowptr, colv, xd, dinv, sv);
    k_h1<<<nblkW, 256, 0, stream>>>(sv, W1, b1, bigA);

    dim3 gemmGrid((N_NODES + BM - 1) / BM, HDIM / BN);
    // layer 2
    k_gemm_scale<<<gemmGrid, 256, 0, stream>>>(bigA, W2, dinv, bigB);
    k_agg<<<nblkW, 256, 0, stream>>>(bigB, rowptr, colv, dinv, b2, bigA);
    // layer 3
    k_gemm_scale<<<gemmGrid, 256, 0, stream>>>(bigA, W3, dinv, bigB);
    k_agg<<<nblkW, 256, 0, stream>>>(bigB, rowptr, colv, dinv, b3, bigA);

    // pooling + head
    k_bounds<<<1, 128, 0, stream>>>(batch, startb, pooled);
    k_pool<<<NGRAPH * 8, 256, 0, stream>>>(bigA, startb, pooled);
    k_feat<<<NGRAPH, 256, 0, stream>>>(pooled, startb, svm, feat);
    k_mlp<<<NGRAPH, 128, 0, stream>>>(feat, Wf1, bf1, Wf2, bf2, out);
}

// Round 2
// 813.449 us; speedup vs baseline: 1.5661x; 1.5661x over previous
//
#include <hip/hip_runtime.h>
#include <math.h>

#define N_NODES 100000
#define N_EDGES 1600000
#define HDIM    256
#define NGRAPH  64

typedef __attribute__((ext_vector_type(8))) short bf16x8;
typedef __attribute__((ext_vector_type(4))) float f32x4;

__device__ __forceinline__ ushort f2b(float f) {
    union { float f; unsigned u; } x; x.f = f;
    unsigned u = x.u;
    unsigned r = u + 0x7fffu + ((u >> 16) & 1u);
    return (ushort)(r >> 16);
}
__device__ __forceinline__ float b2f(ushort h) {
    union { unsigned u; float f; } x; x.u = ((unsigned)h) << 16;
    return x.f;
}

// ---------------- CSR build ----------------
__global__ void k_zero_int(int* __restrict__ p, int n) {
    int i = blockIdx.x * blockDim.x + threadIdx.x;
    if (i < n) p[i] = 0;
}

__global__ void k_count(const int* __restrict__ ei, int* __restrict__ cnt) {
    int e = blockIdx.x * blockDim.x + threadIdx.x;
    if (e < N_EDGES) atomicAdd(&cnt[ei[N_EDGES + e]], 1);
}

__global__ __launch_bounds__(1024) void k_scan(const int* __restrict__ cnt,
                                               int* __restrict__ rowptr) {
    __shared__ int lds[1024];
    int t = threadIdx.x;
    const int chunk = (N_NODES + 1023) / 1024;  // 98
    int i0 = t * chunk;
    int i1 = min(i0 + chunk, N_NODES);
    int s = 0;
    for (int i = i0; i < i1; ++i) s += cnt[i];
    lds[t] = s;
    __syncthreads();
    for (int off = 1; off < 1024; off <<= 1) {
        int v = (t >= off) ? lds[t - off] : 0;
        __syncthreads();
        lds[t] += v;
        __syncthreads();
    }
    int run = (t == 0) ? 0 : lds[t - 1];
    for (int i = i0; i < i1; ++i) { rowptr[i] = run; run += cnt[i]; }
    if (t == 1023) rowptr[N_NODES] = lds[1023];
}

__global__ void k_dinv(const int* __restrict__ cnt, const float* __restrict__ x,
                       float* __restrict__ dinv, float* __restrict__ xd,
                       int* __restrict__ fill) {
    int i = blockIdx.x * blockDim.x + threadIdx.x;
    if (i < N_NODES) {
        float d = (float)(cnt[i] + 1);
        float dv = 1.0f / sqrtf(d);
        dinv[i] = dv;
        xd[i] = x[i] * dv;
        fill[i] = 0;
    }
}

__global__ void k_fill(const int* __restrict__ ei, const int* __restrict__ rowptr,
                       int* __restrict__ fill, int* __restrict__ colv) {
    int e = blockIdx.x * blockDim.x + threadIdx.x;
    if (e < N_EDGES) {
        int d = ei[N_EDGES + e];
        int pos = rowptr[d] + atomicAdd(&fill[d], 1);
        colv[pos] = ei[e];
    }
}

// layer-1 scalar aggregation
__global__ void k_s(const int* __restrict__ rowptr, const int* __restrict__ colv,
                    const float* __restrict__ xd, const float* __restrict__ dinv,
                    float* __restrict__ sv) {
    int i = blockIdx.x * blockDim.x + threadIdx.x;
    if (i >= N_NODES) return;
    float acc = xd[i];
    int s = rowptr[i], e = rowptr[i + 1];
    for (int k = s; k < e; ++k) acc += xd[colv[k]];
    sv[i] = dinv[i] * acc;
}

// h1[i][j] = relu(s[i]*W1[j] + b1[j])  -> bf16
__global__ __launch_bounds__(256) void k_h1(const float* __restrict__ sv,
                                            const float* __restrict__ W1,
                                            const float* __restrict__ b1,
                                            ushort* __restrict__ h) {
    int wid = threadIdx.x >> 6, lane = threadIdx.x & 63;
    int node = blockIdx.x * 4 + wid;
    if (node >= N_NODES) return;
    int c4 = lane * 4;
    float s = sv[node];
    float4 w = *(const float4*)&W1[c4];
    float4 b = *(const float4*)&b1[c4];
    ushort4 o;
    o.x = f2b(fmaxf(s * w.x + b.x, 0.f));
    o.y = f2b(fmaxf(s * w.y + b.y, 0.f));
    o.z = f2b(fmaxf(s * w.z + b.z, 0.f));
    o.w = f2b(fmaxf(s * w.w + b.w, 0.f));
    *(ushort4*)&h[(size_t)node * HDIM + c4] = o;
}

// pack W (f32 [256][256]) into bf16 MFMA B-fragment order:
// Wp[((k0*16 + nt)*64 + lane)*8 + j] = bf16(W[k0*32 + (lane>>4)*8 + j][nt*16 + (lane&15)])
__global__ __launch_bounds__(256) void k_packW(const float* __restrict__ W,
                                               ushort* __restrict__ Wp) {
    int t = blockIdx.x * 256 + threadIdx.x;  // [0, 8192)
    if (t >= 8 * 16 * 64) return;
    int lane = t & 63;
    int nt = (t >> 6) & 15;
    int k0 = t >> 10;
    int col = nt * 16 + (lane & 15);
    int kb = k0 * 32 + (lane >> 4) * 8;
    ushort o[8];
#pragma unroll
    for (int j = 0; j < 8; ++j) o[j] = f2b(W[(size_t)(kb + j) * HDIM + col]);
    *(ushort4*)&Wp[(size_t)t * 8 + 0] = make_ushort4(o[0], o[1], o[2], o[3]);
    *(ushort4*)&Wp[(size_t)t * 8 + 4] = make_ushort4(o[4], o[5], o[6], o[7]);
}

// MFMA GEMM: C[r][c] = dinv[r] * sum_k A[r][k]*W[k][c], A/C bf16, no LDS.
// Block = 4 waves; wave computes 16 rows x 256 cols.
__global__ __launch_bounds__(256) void k_gemm_mfma(const ushort* __restrict__ A,
                                                   const ushort* __restrict__ Wp,
                                                   const float* __restrict__ dinv,
                                                   ushort* __restrict__ C) {
    int tid = threadIdx.x;
    int wave = tid >> 6, lane = tid & 63;
    int r0 = blockIdx.x * 64 + wave * 16;
    int arow = r0 + (lane & 15);
    int kgrp = lane >> 4;
    bool rowok = arow < N_NODES;

    f32x4 acc[16];
#pragma unroll
    for (int nt = 0; nt < 16; ++nt) acc[nt] = (f32x4){0.f, 0.f, 0.f, 0.f};

    const ushort* ap = A + (size_t)(rowok ? arow : 0) * HDIM + kgrp * 8;
#pragma unroll 1
    for (int k0 = 0; k0 < 8; ++k0) {
        bf16x8 a = *(const bf16x8*)(ap + k0 * 32);
        if (!rowok) a = (bf16x8){0, 0, 0, 0, 0, 0, 0, 0};
        const ushort* wp = Wp + ((size_t)k0 * 1024 + lane) * 8;
#pragma unroll
        for (int nt = 0; nt < 16; ++nt) {
            bf16x8 b = *(const bf16x8*)(wp + (size_t)nt * 512);
            acc[nt] = __builtin_amdgcn_mfma_f32_16x16x32_bf16(a, b, acc[nt], 0, 0, 0);
        }
    }

    int rbase = r0 + kgrp * 4;
#pragma unroll
    for (int reg = 0; reg < 4; ++reg) {
        int r = rbase + reg;
        if (r < N_NODES) {
            float dv = dinv[r];
#pragma unroll
            for (int nt = 0; nt < 16; ++nt) {
                float v = acc[nt][reg] * dv;
                C[(size_t)r * HDIM + nt * 16 + (lane & 15)] = f2b(v);
            }
        }
    }
}

// aggregation: h[i] = relu(dinv[i]*(g[i] + sum_src g[src]) + b); bf16 in/out
__global__ __launch_bounds__(256) void k_agg(const ushort* __restrict__ g,
                                             const int* __restrict__ rowptr,
                                             const int* __restrict__ colv,
                                             const float* __restrict__ dinv,
                                             const float* __restrict__ bias,
                                             ushort* __restrict__ hout) {
    int wid = threadIdx.x >> 6, lane = threadIdx.x & 63;
    int node = blockIdx.x * 4 + wid;
    if (node >= N_NODES) return;
    int c4 = lane * 4;
    float4 bv = *(const float4*)&bias[c4];
    ushort4 sv = *(const ushort4*)&g[(size_t)node * HDIM + c4];
    float ax = b2f(sv.x), ay = b2f(sv.y), az = b2f(sv.z), aw = b2f(sv.w);
    int s = rowptr[node], e = rowptr[node + 1];
    int i = s;
    for (; i + 3 < e; i += 4) {
        int s0 = colv[i], s1 = colv[i + 1], s2 = colv[i + 2], s3 = colv[i + 3];
        ushort4 v0 = *(const ushort4*)&g[(size_t)s0 * HDIM + c4];
        ushort4 v1 = *(const ushort4*)&g[(size_t)s1 * HDIM + c4];
        ushort4 v2 = *(const ushort4*)&g[(size_t)s2 * HDIM + c4];
        ushort4 v3 = *(const ushort4*)&g[(size_t)s3 * HDIM + c4];
        ax += b2f(v0.x) + b2f(v1.x) + b2f(v2.x) + b2f(v3.x);
        ay += b2f(v0.y) + b2f(v1.y) + b2f(v2.y) + b2f(v3.y);
        az += b2f(v0.z) + b2f(v1.z) + b2f(v2.z) + b2f(v3.z);
        aw += b2f(v0.w) + b2f(v1.w) + b2f(v2.w) + b2f(v3.w);
    }
    for (; i < e; ++i) {
        int s0 = colv[i];
        ushort4 v0 = *(const ushort4*)&g[(size_t)s0 * HDIM + c4];
        ax += b2f(v0.x); ay += b2f(v0.y); az += b2f(v0.z); aw += b2f(v0.w);
    }
    float dv = dinv[node];
    ushort4 o;
    o.x = f2b(fmaxf(fmaf(ax, dv, bv.x), 0.f));
    o.y = f2b(fmaxf(fmaf(ay, dv, bv.y), 0.f));
    o.z = f2b(fmaxf(fmaf(az, dv, bv.z), 0.f));
    o.w = f2b(fmaxf(fmaf(aw, dv, bv.w), 0.f));
    *(ushort4*)&hout[(size_t)node * HDIM + c4] = o;
}

__global__ __launch_bounds__(128) void k_bounds(const int* __restrict__ batch,
                                                int* __restrict__ startb,
                                                float* __restrict__ pooled) {
    int t = threadIdx.x;
    if (t <= NGRAPH) {
        int lo = 0, hi = N_NODES;
        while (lo < hi) {
            int mid = (lo + hi) >> 1;
            if (batch[mid] < t) lo = mid + 1; else hi = mid;
        }
        startb[t] = lo;
    }
    for (int i = t; i < NGRAPH * HDIM; i += 128) pooled[i] = 0.f;
}

__global__ __launch_bounds__(256) void k_pool(const ushort* __restrict__ h,
                                              const int* __restrict__ startb,
                                              float* __restrict__ pooled) {
    int b = blockIdx.x >> 3, c = blockIdx.x & 7;
    int s0 = startb[b], e0 = startb[b + 1];
    int len = e0 - s0;
    if (len <= 0) return;
    int per = (len + 7) >> 3;
    int is = s0 + c * per;
    int ie = min(is + per, e0);
    if (is >= ie) return;
    int j = threadIdx.x;
    float sum = 0.f;
    for (int n = is; n < ie; ++n) sum += b2f(h[(size_t)n * HDIM + j]);
    atomicAdd(&pooled[b * HDIM + j], sum);
}

__global__ __launch_bounds__(256) void k_feat(const float* __restrict__ pooled,
                                              const int* __restrict__ startb,
                                              const float* __restrict__ svm,
                                              float* __restrict__ feat) {
    int b = blockIdx.x;
    int j = threadIdx.x;
    float cntb = (float)(startb[b + 1] - startb[b]);
    cntb = fmaxf(cntb, 1.0f);
    feat[b * 257 + j] = pooled[b * HDIM + j] / cntb;
    if (j == 0) feat[b * 257 + 256] = svm[b];
}

__global__ __launch_bounds__(128) void k_mlp(const float* __restrict__ feat,
                                             const float* __restrict__ Wf1,
                                             const float* __restrict__ bf1,
                                             const float* __restrict__ Wf2,
                                             const float* __restrict__ bf2,
                                             float* __restrict__ out) {
    __shared__ float fl[257];
    __shared__ float hl[128];
    int b = blockIdx.x;
    int j = threadIdx.x;
    for (int k = j; k < 257; k += 128) fl[k] = feat[b * 257 + k];
    __syncthreads();
    float acc = bf1[j];
    for (int k = 0; k < 257; ++k) acc = fmaf(fl[k], Wf1[k * 128 + j], acc);
    hl[j] = fmaxf(acc, 0.f);
    __syncthreads();
    if (j < 6) {
        float o = bf2[j];
        for (int k = 0; k < 128; ++k) o = fmaf(hl[k], Wf2[k * 6 + j], o);
        out[b * 6 + j] = o;
    }
}

static inline size_t al256(size_t x) { return (x + 255) & ~(size_t)255; }

extern "C" void kernel_launch(void* const* d_in, const int* in_sizes, int n_in,
                              void* d_out, int out_size, void* d_ws, size_t ws_size,
                              hipStream_t stream) {
    const float* x    = (const float*)d_in[0];
    const int*   ei   = (const int*)d_in[1];
    const int*   batch= (const int*)d_in[2];
    const float* svm  = (const float*)d_in[3];
    const float* W1   = (const float*)d_in[4];
    const float* b1   = (const float*)d_in[5];
    const float* W2   = (const float*)d_in[6];
    const float* b2   = (const float*)d_in[7];
    const float* W3   = (const float*)d_in[8];
    const float* b3   = (const float*)d_in[9];
    const float* Wf1  = (const float*)d_in[10];
    const float* bf1  = (const float*)d_in[11];
    const float* Wf2  = (const float*)d_in[12];
    const float* bf2  = (const float*)d_in[13];
    float* out = (float*)d_out;

    char* w = (char*)d_ws;
    int*    cnt    = (int*)w;    w += al256((size_t)N_NODES * 4);
    int*    rowptr = (int*)w;    w += al256((size_t)(N_NODES + 1) * 4);
    int*    fill   = (int*)w;    w += al256((size_t)N_NODES * 4);
    int*    colv   = (int*)w;    w += al256((size_t)N_EDGES * 4);
    float*  dinv   = (float*)w;  w += al256((size_t)N_NODES * 4);
    float*  xd     = (float*)w;  w += al256((size_t)N_NODES * 4);
    float*  sv     = (float*)w;  w += al256((size_t)N_NODES * 4);
    int*    startb = (int*)w;    w += al256(65 * 4);
    float*  pooled = (float*)w;  w += al256((size_t)NGRAPH * HDIM * 4);
    float*  feat   = (float*)w;  w += al256((size_t)NGRAPH * 257 * 4);
    ushort* Wp2    = (ushort*)w; w += al256((size_t)8 * 16 * 64 * 8 * 2);
    ushort* Wp3    = (ushort*)w; w += al256((size_t)8 * 16 * 64 * 8 * 2);
    ushort* bigA   = (ushort*)w; w += al256((size_t)N_NODES * HDIM * 2);
    ushort* bigB   = (ushort*)w; w += al256((size_t)N_NODES * HDIM * 2);

    const int nblkN = (N_NODES + 255) / 256;
    const int nblkE = (N_EDGES + 255) / 256;
    const int nblkW = (N_NODES + 3) / 4;
    const int nblkG = (N_NODES + 63) / 64;  // gemm: 64 rows/block

    // CSR build
    k_zero_int<<<nblkN, 256, 0, stream>>>(cnt, N_NODES);
    k_count<<<nblkE, 256, 0, stream>>>(ei, cnt);
    k_scan<<<1, 1024, 0, stream>>>(cnt, rowptr);
    k_dinv<<<nblkN, 256, 0, stream>>>(cnt, x, dinv, xd, fill);
    k_fill<<<nblkE, 256, 0, stream>>>(ei, rowptr, fill, colv);

    // W packing (layer 2/3)
    k_packW<<<32, 256, 0, stream>>>(W2, Wp2);
    k_packW<<<32, 256, 0, stream>>>(W3, Wp3);

    // layer 1 (rank-1)
    k_s<<<nblkN, 256, 0, stream>>>(rowptr, colv, xd, dinv, sv);
    k_h1<<<nblkW, 256, 0, stream>>>(sv, W1, b1, bigA);

    // layer 2
    k_gemm_mfma<<<nblkG, 256, 0, stream>>>(bigA, Wp2, dinv, bigB);
    k_agg<<<nblkW, 256, 0, stream>>>(bigB, rowptr, colv, dinv, b2, bigA);
    // layer 3
    k_gemm_mfma<<<nblkG, 256, 0, stream>>>(bigA, Wp3, dinv, bigB);
    k_agg<<<nblkW, 256, 0, stream>>>(bigB, rowptr, colv, dinv, b3, bigA);

    // pooling + head
    k_bounds<<<1, 128, 0, stream>>>(batch, startb, pooled);
    k_pool<<<NGRAPH * 8, 256, 0, stream>>>(bigA, startb, pooled);
    k_feat<<<NGRAPH, 256, 0, stream>>>(pooled, startb, svm, feat);
    k_mlp<<<NGRAPH, 128, 0, stream>>>(feat, Wf1, bf1, Wf2, bf2, out);
}

// Round 3
// 644.573 us; speedup vs baseline: 1.9764x; 1.2620x over previous
//
#include <hip/hip_runtime.h>
#include <math.h>

#define N_NODES 100000
#define N_EDGES 1600000
#define HDIM    256
#define NGRAPH  64

#define SCAN_BLK 1024
#define SCAN_NB  ((N_NODES + SCAN_BLK - 1) / SCAN_BLK)  // 98

typedef __attribute__((ext_vector_type(8))) short bf16x8;
typedef __attribute__((ext_vector_type(4))) float f32x4;
typedef __attribute__((ext_vector_type(8))) unsigned short u16x8;

__device__ __forceinline__ ushort f2b(float f) {
    union { float f; unsigned u; } x; x.f = f;
    unsigned u = x.u;
    unsigned r = u + 0x7fffu + ((u >> 16) & 1u);
    return (ushort)(r >> 16);
}
__device__ __forceinline__ float b2f(ushort h) {
    union { unsigned u; float f; } x; x.u = ((unsigned)h) << 16;
    return x.f;
}

// ---------------- CSR build ----------------
__global__ void k_zero_int(int* __restrict__ p, int n) {
    int i = blockIdx.x * blockDim.x + threadIdx.x;
    if (i < n) p[i] = 0;
}

__global__ void k_count(const int* __restrict__ ei, int* __restrict__ cnt) {
    int e = blockIdx.x * blockDim.x + threadIdx.x;
    if (e < N_EDGES) atomicAdd(&cnt[ei[N_EDGES + e]], 1);
}

// phase 1: per-block exclusive scan -> rowptr (local), totals -> bsum
__global__ __launch_bounds__(1024) void k_scan1(const int* __restrict__ cnt,
                                                int* __restrict__ rowptr,
                                                int* __restrict__ bsum) {
    __shared__ int lds[SCAN_BLK];
    int t = threadIdx.x;
    int i = blockIdx.x * SCAN_BLK + t;
    int v = (i < N_NODES) ? cnt[i] : 0;
    lds[t] = v;
    __syncthreads();
    for (int off = 1; off < SCAN_BLK; off <<= 1) {
        int u = (t >= off) ? lds[t - off] : 0;
        __syncthreads();
        lds[t] += u;
        __syncthreads();
    }
    if (i < N_NODES) rowptr[i] = lds[t] - v;  // local exclusive
    if (t == SCAN_BLK - 1) bsum[blockIdx.x] = lds[t];
}

// phase 2: exclusive scan of the 98 block totals (single tiny block)
__global__ __launch_bounds__(128) void k_scan2(int* __restrict__ bsum) {
    __shared__ int lds[128];
    int t = threadIdx.x;
    int v = (t < SCAN_NB) ? bsum[t] : 0;
    lds[t] = v;
    __syncthreads();
    for (int off = 1; off < 128; off <<= 1) {
        int u = (t >= off) ? lds[t - off] : 0;
        __syncthreads();
        lds[t] += u;
        __syncthreads();
    }
    if (t < SCAN_NB) bsum[t] = lds[t] - v;
}

// phase 3: add block offsets; rowptr[N] = E (constant)
__global__ __launch_bounds__(1024) void k_scan3(int* __restrict__ rowptr,
                                                const int* __restrict__ bsum) {
    int i = blockIdx.x * SCAN_BLK + threadIdx.x;
    if (i < N_NODES) rowptr[i] += bsum[blockIdx.x];
    if (i == 0) rowptr[N_NODES] = N_EDGES;
}

__global__ void k_dinv(const int* __restrict__ cnt, const float* __restrict__ x,
                       float* __restrict__ dinv, float* __restrict__ xd,
                       int* __restrict__ fill) {
    int i = blockIdx.x * blockDim.x + threadIdx.x;
    if (i < N_NODES) {
        float d = (float)(cnt[i] + 1);
        float dv = 1.0f / sqrtf(d);
        dinv[i] = dv;
        xd[i] = x[i] * dv;
        fill[i] = 0;
    }
}

__global__ void k_fill(const int* __restrict__ ei, const int* __restrict__ rowptr,
                       int* __restrict__ fill, int* __restrict__ colv) {
    int e = blockIdx.x * blockDim.x + threadIdx.x;
    if (e < N_EDGES) {
        int d = ei[N_EDGES + e];
        int pos = rowptr[d] + atomicAdd(&fill[d], 1);
        colv[pos] = ei[e];
    }
}

// layer-1 scalar aggregation
__global__ void k_s(const int* __restrict__ rowptr, const int* __restrict__ colv,
                    const float* __restrict__ xd, const float* __restrict__ dinv,
                    float* __restrict__ sv) {
    int i = blockIdx.x * blockDim.x + threadIdx.x;
    if (i >= N_NODES) return;
    float acc = xd[i];
    int s = rowptr[i], e = rowptr[i + 1];
    for (int k = s; k < e; ++k) acc += xd[colv[k]];
    sv[i] = dinv[i] * acc;
}

// h1[i][j] = relu(s[i]*W1[j] + b1[j])  -> bf16
__global__ __launch_bounds__(256) void k_h1(const float* __restrict__ sv,
                                            const float* __restrict__ W1,
                                            const float* __restrict__ b1,
                                            ushort* __restrict__ h) {
    int wid = threadIdx.x >> 6, lane = threadIdx.x & 63;
    int node = blockIdx.x * 4 + wid;
    if (node >= N_NODES) return;
    int c4 = lane * 4;
    float s = sv[node];
    float4 w = *(const float4*)&W1[c4];
    float4 b = *(const float4*)&b1[c4];
    ushort4 o;
    o.x = f2b(fmaxf(s * w.x + b.x, 0.f));
    o.y = f2b(fmaxf(s * w.y + b.y, 0.f));
    o.z = f2b(fmaxf(s * w.z + b.z, 0.f));
    o.w = f2b(fmaxf(s * w.w + b.w, 0.f));
    *(ushort4*)&h[(size_t)node * HDIM + c4] = o;
}

// pack W (f32 [256][256]) into bf16 MFMA B-fragment order
__global__ __launch_bounds__(256) void k_packW(const float* __restrict__ W,
                                               ushort* __restrict__ Wp) {
    int t = blockIdx.x * 256 + threadIdx.x;  // [0, 8192)
    if (t >= 8 * 16 * 64) return;
    int lane = t & 63;
    int nt = (t >> 6) & 15;
    int k0 = t >> 10;
    int col = nt * 16 + (lane & 15);
    int kb = k0 * 32 + (lane >> 4) * 8;
    ushort o[8];
#pragma unroll
    for (int j = 0; j < 8; ++j) o[j] = f2b(W[(size_t)(kb + j) * HDIM + col]);
    *(ushort4*)&Wp[(size_t)t * 8 + 0] = make_ushort4(o[0], o[1], o[2], o[3]);
    *(ushort4*)&Wp[(size_t)t * 8 + 4] = make_ushort4(o[4], o[5], o[6], o[7]);
}

// MFMA GEMM: C[r][c] = dinv[r] * sum_k A[r][k]*W[k][c], A/C bf16, no LDS.
__global__ __launch_bounds__(256) void k_gemm_mfma(const ushort* __restrict__ A,
                                                   const ushort* __restrict__ Wp,
                                                   const float* __restrict__ dinv,
                                                   ushort* __restrict__ C) {
    int tid = threadIdx.x;
    int wave = tid >> 6, lane = tid & 63;
    int r0 = blockIdx.x * 64 + wave * 16;
    int arow = r0 + (lane & 15);
    int kgrp = lane >> 4;
    bool rowok = arow < N_NODES;

    f32x4 acc[16];
#pragma unroll
    for (int nt = 0; nt < 16; ++nt) acc[nt] = (f32x4){0.f, 0.f, 0.f, 0.f};

    const ushort* ap = A + (size_t)(rowok ? arow : 0) * HDIM + kgrp * 8;
#pragma unroll 1
    for (int k0 = 0; k0 < 8; ++k0) {
        bf16x8 a = *(const bf16x8*)(ap + k0 * 32);
        if (!rowok) a = (bf16x8){0, 0, 0, 0, 0, 0, 0, 0};
        const ushort* wp = Wp + ((size_t)k0 * 1024 + lane) * 8;
#pragma unroll
        for (int nt = 0; nt < 16; ++nt) {
            bf16x8 b = *(const bf16x8*)(wp + (size_t)nt * 512);
            acc[nt] = __builtin_amdgcn_mfma_f32_16x16x32_bf16(a, b, acc[nt], 0, 0, 0);
        }
    }

    int rbase = r0 + kgrp * 4;
#pragma unroll
    for (int reg = 0; reg < 4; ++reg) {
        int r = rbase + reg;
        if (r < N_NODES) {
            float dv = dinv[r];
#pragma unroll
            for (int nt = 0; nt < 16; ++nt) {
                float v = acc[nt][reg] * dv;
                C[(size_t)r * HDIM + nt * 16 + (lane & 15)] = f2b(v);
            }
        }
    }
}

// aggregation: h[i] = relu(dinv[i]*(g[i] + sum_src g[src]) + b)
// wave per node; half-wave (32 lanes x 16B) covers one 512B row;
// full wave processes 2 neighbors per iteration.
__global__ __launch_bounds__(256) void k_agg(const ushort* __restrict__ g,
                                             const int* __restrict__ rowptr,
                                             const int* __restrict__ colv,
                                             const float* __restrict__ dinv,
                                             const float* __restrict__ bias,
                                             ushort* __restrict__ hout) {
    int wid = threadIdx.x >> 6, lane = threadIdx.x & 63;
    int node = blockIdx.x * 4 + wid;
    if (node >= N_NODES) return;
    int half = lane >> 5;
    int l32 = lane & 31;
    int c8 = l32 * 8;
    float acc[8];
    if (half == 0) {
        u16x8 v = *(const u16x8*)&g[(size_t)node * HDIM + c8];
#pragma unroll
        for (int j = 0; j < 8; ++j) acc[j] = b2f(v[j]);
    } else {
#pragma unroll
        for (int j = 0; j < 8; ++j) acc[j] = 0.f;
    }
    int s = rowptr[node], e = rowptr[node + 1];
    int i = s;
#pragma unroll 2
    for (; i + 2 <= e; i += 2) {
        int n = colv[i + half];
        u16x8 v = *(const u16x8*)&g[(size_t)n * HDIM + c8];
#pragma unroll
        for (int j = 0; j < 8; ++j) acc[j] += b2f(v[j]);
    }
    if (i < e && half == 0) {
        int n = colv[i];
        u16x8 v = *(const u16x8*)&g[(size_t)n * HDIM + c8];
#pragma unroll
        for (int j = 0; j < 8; ++j) acc[j] += b2f(v[j]);
    }
#pragma unroll
    for (int j = 0; j < 8; ++j) acc[j] += __shfl_xor(acc[j], 32);
    if (half == 0) {
        float dv = dinv[node];
        float4 bl = *(const float4*)&bias[c8];
        float4 bh = *(const float4*)&bias[c8 + 4];
        float bj[8] = {bl.x, bl.y, bl.z, bl.w, bh.x, bh.y, bh.z, bh.w};
        u16x8 ov;
#pragma unroll
        for (int j = 0; j < 8; ++j)
            ov[j] = f2b(fmaxf(fmaf(acc[j], dv, bj[j]), 0.f));
        *(u16x8*)&hout[(size_t)node * HDIM + c8] = ov;
    }
}

__global__ __launch_bounds__(128) void k_bounds(const int* __restrict__ batch,
                                                int* __restrict__ startb,
                                                float* __restrict__ pooled) {
    int t = threadIdx.x;
    if (t <= NGRAPH) {
        int lo = 0, hi = N_NODES;
        while (lo < hi) {
            int mid = (lo + hi) >> 1;
            if (batch[mid] < t) lo = mid + 1; else hi = mid;
        }
        startb[t] = lo;
    }
    for (int i = t; i < NGRAPH * HDIM; i += 128) pooled[i] = 0.f;
}

__global__ __launch_bounds__(256) void k_pool(const ushort* __restrict__ h,
                                              const int* __restrict__ startb,
                                              float* __restrict__ pooled) {
    int b = blockIdx.x >> 3, c = blockIdx.x & 7;
    int s0 = startb[b], e0 = startb[b + 1];
    int len = e0 - s0;
    if (len <= 0) return;
    int per = (len + 7) >> 3;
    int is = s0 + c * per;
    int ie = min(is + per, e0);
    if (is >= ie) return;
    int j = threadIdx.x;
    float sum = 0.f;
    for (int n = is; n < ie; ++n) sum += b2f(h[(size_t)n * HDIM + j]);
    atomicAdd(&pooled[b * HDIM + j], sum);
}

__global__ __launch_bounds__(256) void k_feat(const float* __restrict__ pooled,
                                              const int* __restrict__ startb,
                                              const float* __restrict__ svm,
                                              float* __restrict__ feat) {
    int b = blockIdx.x;
    int j = threadIdx.x;
    float cntb = (float)(startb[b + 1] - startb[b]);
    cntb = fmaxf(cntb, 1.0f);
    feat[b * 257 + j] = pooled[b * HDIM + j] / cntb;
    if (j == 0) feat[b * 257 + 256] = svm[b];
}

__global__ __launch_bounds__(128) void k_mlp(const float* __restrict__ feat,
                                             const float* __restrict__ Wf1,
                                             const float* __restrict__ bf1,
                                             const float* __restrict__ Wf2,
                                             const float* __restrict__ bf2,
                                             float* __restrict__ out) {
    __shared__ float fl[257];
    __shared__ float hl[128];
    int b = blockIdx.x;
    int j = threadIdx.x;
    for (int k = j; k < 257; k += 128) fl[k] = feat[b * 257 + k];
    __syncthreads();
    float acc = bf1[j];
    for (int k = 0; k < 257; ++k) acc = fmaf(fl[k], Wf1[k * 128 + j], acc);
    hl[j] = fmaxf(acc, 0.f);
    __syncthreads();
    if (j < 6) {
        float o = bf2[j];
        for (int k = 0; k < 128; ++k) o = fmaf(hl[k], Wf2[k * 6 + j], o);
        out[b * 6 + j] = o;
    }
}

static inline size_t al256(size_t x) { return (x + 255) & ~(size_t)255; }

extern "C" void kernel_launch(void* const* d_in, const int* in_sizes, int n_in,
                              void* d_out, int out_size, void* d_ws, size_t ws_size,
                              hipStream_t stream) {
    const float* x    = (const float*)d_in[0];
    const int*   ei   = (const int*)d_in[1];
    const int*   batch= (const int*)d_in[2];
    const float* svm  = (const float*)d_in[3];
    const float* W1   = (const float*)d_in[4];
    const float* b1   = (const float*)d_in[5];
    const float* W2   = (const float*)d_in[6];
    const float* b2   = (const float*)d_in[7];
    const float* W3   = (const float*)d_in[8];
    const float* b3   = (const float*)d_in[9];
    const float* Wf1  = (const float*)d_in[10];
    const float* bf1  = (const float*)d_in[11];
    const float* Wf2  = (const float*)d_in[12];
    const float* bf2  = (const float*)d_in[13];
    float* out = (float*)d_out;

    char* w = (char*)d_ws;
    int*    cnt    = (int*)w;    w += al256((size_t)N_NODES * 4);
    int*    rowptr = (int*)w;    w += al256((size_t)(N_NODES + 1) * 4);
    int*    fill   = (int*)w;    w += al256((size_t)N_NODES * 4);
    int*    colv   = (int*)w;    w += al256((size_t)N_EDGES * 4);
    float*  dinv   = (float*)w;  w += al256((size_t)N_NODES * 4);
    float*  xd     = (float*)w;  w += al256((size_t)N_NODES * 4);
    float*  sv     = (float*)w;  w += al256((size_t)N_NODES * 4);
    int*    startb = (int*)w;    w += al256(65 * 4);
    int*    bsum   = (int*)w;    w += al256((size_t)SCAN_NB * 4);
    float*  pooled = (float*)w;  w += al256((size_t)NGRAPH * HDIM * 4);
    float*  feat   = (float*)w;  w += al256((size_t)NGRAPH * 257 * 4);
    ushort* Wp2    = (ushort*)w; w += al256((size_t)8 * 16 * 64 * 8 * 2);
    ushort* Wp3    = (ushort*)w; w += al256((size_t)8 * 16 * 64 * 8 * 2);
    ushort* bigA   = (ushort*)w; w += al256((size_t)N_NODES * HDIM * 2);
    ushort* bigB   = (ushort*)w; w += al256((size_t)N_NODES * HDIM * 2);

    const int nblkN = (N_NODES + 255) / 256;
    const int nblkE = (N_EDGES + 255) / 256;
    const int nblkW = (N_NODES + 3) / 4;
    const int nblkG = (N_NODES + 63) / 64;

    // CSR build
    k_zero_int<<<nblkN, 256, 0, stream>>>(cnt, N_NODES);
    k_count<<<nblkE, 256, 0, stream>>>(ei, cnt);
    k_scan1<<<SCAN_NB, SCAN_BLK, 0, stream>>>(cnt, rowptr, bsum);
    k_scan2<<<1, 128, 0, stream>>>(bsum);
    k_scan3<<<SCAN_NB, SCAN_BLK, 0, stream>>>(rowptr, bsum);
    k_dinv<<<nblkN, 256, 0, stream>>>(cnt, x, dinv, xd, fill);
    k_fill<<<nblkE, 256, 0, stream>>>(ei, rowptr, fill, colv);

    // W packing (layer 2/3)
    k_packW<<<32, 256, 0, stream>>>(W2, Wp2);
    k_packW<<<32, 256, 0, stream>>>(W3, Wp3);

    // layer 1 (rank-1)
    k_s<<<nblkN, 256, 0, stream>>>(rowptr, colv, xd, dinv, sv);
    k_h1<<<nblkW, 256, 0, stream>>>(sv, W1, b1, bigA);

    // layer 2
    k_gemm_mfma<<<nblkG, 256, 0, stream>>>(bigA, Wp2, dinv, bigB);
    k_agg<<<nblkW, 256, 0, stream>>>(bigB, rowptr, colv, dinv, b2, bigA);
    // layer 3
    k_gemm_mfma<<<nblkG, 256, 0, stream>>>(bigA, Wp3, dinv, bigB);
    k_agg<<<nblkW, 256, 0, stream>>>(bigB, rowptr, colv, dinv, b3, bigA);

    // pooling + head
    k_bounds<<<1, 128, 0, stream>>>(batch, startb, pooled);
    k_pool<<<NGRAPH * 8, 256, 0, stream>>>(bigA, startb, pooled);
    k_feat<<<NGRAPH, 256, 0, stream>>>(pooled, startb, svm, feat);
    k_mlp<<<NGRAPH, 128, 0, stream>>>(feat, Wf1, bf1, Wf2, bf2, out);
}